// Round 13
// baseline (1730.672 us; speedup 1.0000x reference)
//
#include <hip/hip_runtime.h>

#define TT 2000
#define BB 128
#define DD 64
#define UU 128
#define G3U 384          // 3*U
#define NROW (BB * TT)   // 256000 rows of x / gx

typedef __attribute__((ext_vector_type(4))) float f4v;

// ---------- helpers ----------
__device__ __forceinline__ float4 fma4(float s, float4 w, float4 a) {
  a.x = fmaf(s, w.x, a.x);
  a.y = fmaf(s, w.y, a.y);
  a.z = fmaf(s, w.z, a.z);
  a.w = fmaf(s, w.w, a.w);
  return a;
}
// packed dual-FP32 FMA / MUL
__device__ __forceinline__ void pk_fma(float2& acc, float2 a, float2 b) {
  asm("v_pk_fma_f32 %0, %1, %2, %0" : "+v"(acc) : "v"(a), "v"(b));
}
__device__ __forceinline__ float2 pk_mul(float2 a, float2 b) {
  float2 r;
  asm("v_pk_mul_f32 %0, %1, %2" : "=v"(r) : "v"(a), "v"(b));
  return r;
}
// DPP via builtin ONLY (compiler inserts the VALU->DPP hazard waits; inline-asm
// DPP in r7/r8 silently corrupted the reduction).
template <int CTRL>
__device__ __forceinline__ float dpp_mov(float v) {
  return __int_as_float(__builtin_amdgcn_update_dpp(0, __float_as_int(v), CTRL, 0xF, 0xF, true));
}
// sum across an aligned 8-lane group
__device__ __forceinline__ float red8(float2 a) {
  float v = a.x + a.y;
  v += dpp_mov<0xB1>(v);   // lane ^ 1
  v += dpp_mov<0x4E>(v);   // lane ^ 2
  v += dpp_mov<0x141>(v);  // row_half_mirror: crosses quads within 8
  return v;
}
__device__ __forceinline__ float sig_(float v) {  // exact at +-inf
  float e = __builtin_amdgcn_exp2f(-1.442695041f * v);
  return __builtin_amdgcn_rcpf(1.0f + e);
}
__device__ __forceinline__ float tanh_(float v) {
  float e = __builtin_amdgcn_exp2f(-2.885390082f * v);
  float r = __builtin_amdgcn_rcpf(1.0f + e);
  return fmaf(2.0f, r, -1.0f);
}
// LDS-only barrier: no vmcnt(0) drain -> gx prefetch loads / out stores stay
// in flight across steps. sched_barrier fences hoisting (rule #18).
__device__ __forceinline__ void bar_lds() {
  __builtin_amdgcn_sched_barrier(0);
  asm volatile("s_waitcnt lgkmcnt(0)" ::: "memory");
  __builtin_amdgcn_s_barrier();
  __builtin_amdgcn_sched_barrier(0);
}

// ---------- prologue: gx[r][c] = sum_k x[r][k]*(kern[k][c]+akern[k][c]) + bias[c] ----------
__global__ __launch_bounds__(256, 2)
void gx_kernel(const float* __restrict__ x, const float* __restrict__ kern,
               const float* __restrict__ akern, const float* __restrict__ bias,
               float* __restrict__ gx) {
  __shared__ __align__(16) float xT[64][68];
  __shared__ __align__(16) float Ws[64][68];
  const int r0 = blockIdx.x * 64;
  const int c0 = blockIdx.y * 64;
  const int tid = threadIdx.x;

  {
    const int row = tid >> 2;
    const int kb = (tid & 3) * 16;
#pragma unroll
    for (int i = 0; i < 4; ++i) {
      float4 v = *(const float4*)&x[(size_t)(r0 + row) * DD + kb + i * 4];
      xT[kb + i * 4 + 0][row] = v.x;
      xT[kb + i * 4 + 1][row] = v.y;
      xT[kb + i * 4 + 2][row] = v.z;
      xT[kb + i * 4 + 3][row] = v.w;
    }
    const int kk = tid >> 2;
    const int jb = (tid & 3) * 16;
#pragma unroll
    for (int i = 0; i < 4; ++i) {
      const size_t off = (size_t)kk * G3U + c0 + jb + i * 4;
      float4 a = *(const float4*)&kern[off];
      float4 c = *(const float4*)&akern[off];
      *(float4*)&Ws[kk][jb + i * 4] = make_float4(a.x + c.x, a.y + c.y, a.z + c.z, a.w + c.w);
    }
  }
  __syncthreads();

  const int tx = tid & 15, ty = tid >> 4;
  float4 acc0 = make_float4(0, 0, 0, 0), acc1 = acc0, acc2 = acc0, acc3 = acc0;
#pragma unroll
  for (int k = 0; k < 64; ++k) {
    float4 wv = *(const float4*)&Ws[k][tx * 4];
    float4 xv = *(const float4*)&xT[k][ty * 4];
    acc0 = fma4(xv.x, wv, acc0);
    acc1 = fma4(xv.y, wv, acc1);
    acc2 = fma4(xv.z, wv, acc2);
    acc3 = fma4(xv.w, wv, acc3);
  }
  float4 bv = *(const float4*)&bias[c0 + tx * 4];
  acc0.x += bv.x; acc0.y += bv.y; acc0.z += bv.z; acc0.w += bv.w;
  acc1.x += bv.x; acc1.y += bv.y; acc1.z += bv.z; acc1.w += bv.w;
  acc2.x += bv.x; acc2.y += bv.y; acc2.z += bv.z; acc2.w += bv.w;
  acc3.x += bv.x; acc3.y += bv.y; acc3.z += bv.z; acc3.w += bv.w;
  float* g0 = &gx[(size_t)(r0 + ty * 4) * G3U + c0 + tx * 4];
  *(float4*)(g0 + 0 * G3U) = acc0;
  *(float4*)(g0 + 1 * G3U) = acc1;
  *(float4*)(g0 + 2 * G3U) = acc2;
  *(float4*)(g0 + 3 * G3U) = acc3;
}

// ---------- recurrence (r12 + register-pinned weights) ----------
// One block per batch row, 512 threads = 8 waves.
// KEY FIX (r13): VGPR_Count was 88 < 96 weight floats regardless of
// launch_bounds -> the compiler was REMATERIALIZING the weight loads inside
// the loop (~24 global_load_dwordx2 / thread / step, L2-resident but ~200cyc
// latency + VMEM issue pressure in lockstep). An opaque identity asm on each
// weight pins it live in VGPRs for the kernel lifetime (asm results cannot be
// rematerialized). Budget fine: ~150 < 256 at 8 waves/CU.
// Group = 8 lanes: g = tid>>3 (0..63), j = tid&7 owns k-slice [16j, 16j+16).
// Group g owns cols: z {2g,2g+1}, r {128+2g,..}, hh {2g,..}. z matvec sums are
// accumulated in ph1 but reduced+activated in ph2 (under the Rb read shadow).
// h double-buffered by parity; fp32 exchange; LDS rows stride 36 floats.
__global__ __launch_bounds__(512, 1)
void gru_rec(const float* __restrict__ gx, const float* __restrict__ rk,
             const float* __restrict__ h0, float* __restrict__ out) {
  const int b = blockIdx.x;
  const int tid = threadIdx.x;
  const int g = tid >> 3;        // 0..63
  const int j = tid & 7;         // k-slice index
  const int kbase = j * 16;

  __shared__ __align__(16) float hb[2][8][36];   // h, value k at [p][k>>4][k&15]
  __shared__ __align__(16) float rhb[8][36];     // r*h, same layout

  const float* gxb = gx + (size_t)b * TT * G3U;
  float* outb = out + (size_t)b * TT * UU;

  // weights in VGPRs, packed along k:
  //   wZ[c][m] = (rk[kbase+2m][2g+c],     rk[kbase+2m+1][2g+c])
  //   wR[c][m] = (rk[kbase+2m][128+2g+c], rk[kbase+2m+1][128+2g+c])
  //   wH[c][m] = (rk[kbase+2m][256+2g+c], rk[kbase+2m+1][256+2g+c])
  float2 wZ[2][8], wR[2][8], wH[2][8];
#pragma unroll
  for (int c = 0; c < 2; ++c) {
#pragma unroll
    for (int m = 0; m < 8; ++m) {
      const float* r0p = rk + (size_t)(kbase + 2 * m) * G3U;
      const float* r1p = rk + (size_t)(kbase + 2 * m + 1) * G3U;
      wZ[c][m] = make_float2(r0p[2 * g + c], r1p[2 * g + c]);
      wR[c][m] = make_float2(r0p[128 + 2 * g + c], r1p[128 + 2 * g + c]);
      wH[c][m] = make_float2(r0p[256 + 2 * g + c], r1p[256 + 2 * g + c]);
    }
  }
  // pin: opaque identity -> values must stay live in VGPRs (no remat)
#pragma unroll
  for (int c = 0; c < 2; ++c) {
#pragma unroll
    for (int m = 0; m < 8; ++m) {
      asm volatile("" : "+v"(wZ[c][m]));
      asm volatile("" : "+v"(wR[c][m]));
      asm volatile("" : "+v"(wH[c][m]));
    }
  }

  if (tid < UU) hb[0][tid >> 4][tid & 15] = h0[(size_t)b * UU + tid];

  // 4-deep prefetch ring (named regs; rule #20: no runtime indexing)
  float2 gz0, gz1, gz2, gz3, gr0, gr1, gr2, gr3, gh0, gh1, gh2, gh3;
  {
    const float* gp0 = gxb + 2 * g;
    gz0 = *(const float2*)(gp0 + 0 * G3U); gr0 = *(const float2*)(gp0 + 0 * G3U + 128); gh0 = *(const float2*)(gp0 + 0 * G3U + 256);
    gz1 = *(const float2*)(gp0 + 1 * G3U); gr1 = *(const float2*)(gp0 + 1 * G3U + 128); gh1 = *(const float2*)(gp0 + 1 * G3U + 256);
    gz2 = *(const float2*)(gp0 + 2 * G3U); gr2 = *(const float2*)(gp0 + 2 * G3U + 128); gh2 = *(const float2*)(gp0 + 2 * G3U + 256);
    gz3 = *(const float2*)(gp0 + 3 * G3U); gr3 = *(const float2*)(gp0 + 3 * G3U + 128); gh3 = *(const float2*)(gp0 + 3 * G3U + 256);
  }

  bar_lds();

#define STEP(T_IDX, P, PF, GZ, GR, GH)                                        \
  do {                                                                        \
    float2 curz = (GZ), curr = (GR), curh = (GH);                             \
    if (PF) {                                                                 \
      const float* gp = gxb + (size_t)((T_IDX) + 4) * G3U + 2 * g;            \
      (GZ) = *(const float2*)gp;                                              \
      (GR) = *(const float2*)(gp + 128);                                      \
      (GH) = *(const float2*)(gp + 256);                                      \
    }                                                                         \
    /* ---- phase 1: r critical path; z accumulated only ---- */              \
    float4 ha = *(const float4*)&hb[P][j][0];                                 \
    float4 hbv = *(const float4*)&hb[P][j][4];                                \
    float4 hc = *(const float4*)&hb[P][j][8];                                 \
    float4 hd = *(const float4*)&hb[P][j][12];                                \
    float2 hg = make_float2(0.f, 0.f);                                        \
    if (j == 0) hg = *(const float2*)&hb[P][g >> 3][(2 * g) & 15];            \
    float2 hp[8] = {make_float2(ha.x, ha.y),   make_float2(ha.z, ha.w),       \
                    make_float2(hbv.x, hbv.y), make_float2(hbv.z, hbv.w),     \
                    make_float2(hc.x, hc.y),   make_float2(hc.z, hc.w),       \
                    make_float2(hd.x, hd.y),   make_float2(hd.z, hd.w)};      \
    float2 aR0 = pk_mul(hp[0], wR[0][0]);                                     \
    float2 aR1 = pk_mul(hp[0], wR[1][0]);                                     \
    float2 aZ0 = pk_mul(hp[0], wZ[0][0]);                                     \
    float2 aZ1 = pk_mul(hp[0], wZ[1][0]);                                     \
    _Pragma("unroll") for (int m = 1; m < 8; ++m) {                           \
      pk_fma(aR0, hp[m], wR[0][m]);                                           \
      pk_fma(aR1, hp[m], wR[1][m]);                                           \
      pk_fma(aZ0, hp[m], wZ[0][m]);                                           \
      pk_fma(aZ1, hp[m], wZ[1][m]);                                           \
    }                                                                         \
    float r0 = sig_(red8(aR0) + curr.x);                                      \
    float r1 = sig_(red8(aR1) + curr.y);                                      \
    if (j == 0)                                                               \
      *(float2*)&rhb[g >> 3][(2 * g) & 15] = make_float2(r0 * hg.x, r1 * hg.y); \
    bar_lds(); /* B1: rh published */                                         \
    /* ---- phase 2: hh + deferred z + blend ---- */                          \
    float4 ra = *(const float4*)&rhb[j][0];                                   \
    float4 rb_ = *(const float4*)&rhb[j][4];                                  \
    float4 rc = *(const float4*)&rhb[j][8];                                   \
    float4 rd = *(const float4*)&rhb[j][12];                                  \
    /* z reduce+sigmoid under the Rb read shadow (register-only) */           \
    float z0 = sig_(red8(aZ0) + curz.x);                                      \
    float z1 = sig_(red8(aZ1) + curz.y);                                      \
    float2 rp[8] = {make_float2(ra.x, ra.y),   make_float2(ra.z, ra.w),       \
                    make_float2(rb_.x, rb_.y), make_float2(rb_.z, rb_.w),     \
                    make_float2(rc.x, rc.y),   make_float2(rc.z, rc.w),       \
                    make_float2(rd.x, rd.y),   make_float2(rd.z, rd.w)};      \
    float2 aH0 = pk_mul(rp[0], wH[0][0]);                                     \
    float2 aH1 = pk_mul(rp[0], wH[1][0]);                                     \
    _Pragma("unroll") for (int m = 1; m < 8; ++m) {                           \
      pk_fma(aH0, rp[m], wH[0][m]);                                           \
      pk_fma(aH1, rp[m], wH[1][m]);                                           \
    }                                                                         \
    float hh0 = tanh_(red8(aH0) + curh.x);                                    \
    float hh1 = tanh_(red8(aH1) + curh.y);                                    \
    float hn0 = fmaf(z0, hg.x - hh0, hh0);                                    \
    float hn1 = fmaf(z1, hg.y - hh1, hh1);                                    \
    if (j == 0) {                                                             \
      *(float2*)&hb[(P) ^ 1][g >> 3][(2 * g) & 15] = make_float2(hn0, hn1);   \
      *(float2*)&outb[(size_t)(T_IDX)*UU + 2 * g] = make_float2(hn0, hn1);    \
    }                                                                         \
    bar_lds(); /* B2: h published */                                          \
  } while (0)

  // main loop: unconditional prefetch (t+4 <= 1999 safe for t <= 1995)
  for (int t = 0; t < TT - 4; t += 4) {
    STEP(t + 0, 0, 1, gz0, gr0, gh0);
    STEP(t + 1, 1, 1, gz1, gr1, gh1);
    STEP(t + 2, 0, 1, gz2, gr2, gh2);
    STEP(t + 3, 1, 1, gz3, gr3, gh3);
  }
  // tail: steps 1996..1999, no prefetch
  STEP(TT - 4, 0, 0, gz0, gr0, gh0);
  STEP(TT - 3, 1, 0, gz1, gr1, gh1);
  STEP(TT - 2, 0, 0, gz2, gr2, gh2);
  STEP(TT - 1, 1, 0, gz3, gr3, gh3);
#undef STEP
}

extern "C" void kernel_launch(void* const* d_in, const int* in_sizes, int n_in,
                              void* d_out, int out_size, void* d_ws, size_t ws_size,
                              hipStream_t stream) {
  const float* x = (const float*)d_in[0];
  const float* kern = (const float*)d_in[1];
  const float* rk = (const float*)d_in[2];
  const float* akern = (const float*)d_in[3];
  // d_in[4] attention_w, d_in[5] attention_u, d_in[7] attention_b, d_in[8] attention_v:
  // mathematically dead (softmax over singleton axis == 1, so z_hat == x_t).
  const float* bias = (const float*)d_in[6];
  const float* h0 = (const float*)d_in[9];
  float* out = (float*)d_out;
  float* gx = (float*)d_ws;  // [NROW][384] fp32 = 393,216,000 bytes

  gx_kernel<<<dim3(NROW / 64, G3U / 64), 256, 0, stream>>>(x, kern, akern, bias, gx);
  gru_rec<<<dim3(BB), 512, 0, stream>>>(gx, rk, h0, out);
}